// Round 6
// baseline (495.539 us; speedup 1.0000x reference)
//
#include <hip/hip_runtime.h>
#include <hip/hip_bf16.h>

// Problem constants (reference: WORLD_SIZE=8, M_LOCAL=1024, K=4096, N=4096)
#define M_TOTAL 8192
#define KDIM    4096
#define NDIM    4096

// GEMM tiling: 256x256 tile, BK=64, 512 threads (8 waves as 2M x 4N),
// per-wave output 128x64. 2 LDS buffers (64 KiB each). Per K-64 tile:
// boundary {stage full next tile (8 gloads), vmcnt(8), barrier} then 4
// phases, each {ds-reads -> barrier -> lgkm0 -> 16 MFMA (setprio) -> barrier}.
#define BK 64
#define NTT 64                  // number of K-tiles

typedef __bf16 bf16x8 __attribute__((ext_vector_type(8)));
typedef float  f32x4  __attribute__((ext_vector_type(4)));

// ---------------------------------------------------------------------------
// fp32 -> bf16 (RNE), 8 elems/thread, 16B stores; A and W in one launch
// (unchanged — isolates the GEMM change)
// ---------------------------------------------------------------------------
__device__ __forceinline__ unsigned short f32_to_bf16_rne(unsigned u) {
    unsigned r = u + 0x7fffu + ((u >> 16) & 1u);
    return (unsigned short)(r >> 16);
}

__device__ __forceinline__ void cvt8(const float* __restrict__ s,
                                     unsigned short* __restrict__ d) {
    const uint4* sp = (const uint4*)s;
    uint4 x = sp[0];
    uint4 y = sp[1];
    uint4 o;
    o.x = (unsigned)f32_to_bf16_rne(x.x) | ((unsigned)f32_to_bf16_rne(x.y) << 16);
    o.y = (unsigned)f32_to_bf16_rne(x.z) | ((unsigned)f32_to_bf16_rne(x.w) << 16);
    o.z = (unsigned)f32_to_bf16_rne(y.x) | ((unsigned)f32_to_bf16_rne(y.y) << 16);
    o.w = (unsigned)f32_to_bf16_rne(y.z) | ((unsigned)f32_to_bf16_rne(y.w) << 16);
    *(uint4*)d = o;
}

__global__ __launch_bounds__(256) void cvt_both(const float* __restrict__ A,
                                                unsigned short* __restrict__ Abf,
                                                long nA,
                                                const float* __restrict__ W,
                                                unsigned short* __restrict__ Wbf) {
    long i = ((long)blockIdx.x * 256 + threadIdx.x) * 8;
    if (i < nA) {
        cvt8(A + i, Abf + i);
    } else {
        long j = i - nA;
        cvt8(W + j, Wbf + j);
    }
}

// ---------------------------------------------------------------------------
// async global -> LDS, 16B per lane (wave-uniform LDS base + lane*16)
// ---------------------------------------------------------------------------
__device__ __forceinline__ void gload_lds16(const unsigned short* g, unsigned short* l) {
    __builtin_amdgcn_global_load_lds(
        (const __attribute__((address_space(1))) unsigned int*)g,
        (__attribute__((address_space(3))) unsigned int*)l,
        16, 0, 0);
}

// ---------------------------------------------------------------------------
// C[M,N] = A[M,K] * B[N,K]^T   (bf16 in, fp32 out)
//
// FIXES vs round 5 (which failed correctness):
//  (1) A-read addressing: aoff[16] holds ALL 8 mi-rows (wm*128 + mi*16 + r,
//      mi 0..7); aT = aoff[0..7], aB = aoff[8..15]. No bogus half*8192 offset
//      (r5 double-counted: wm=1 waves read past the A region).
//  (2) Residency: ph1 reads touch BOTH A-halves and BOTH B-halves (wm=1
//      waves need A-half1; every wn needs its B rows) -> whole tile must be
//      resident at first read. Boundary-block staging:
//
//   tile t (buf d=t&1):
//     STAGE all 8 loads of tile t+1 -> buf d^1   (buf d^1's last readers =
//         tile t-1, drained by their ph3 lgkm0 >=2 barriers ago)
//     s_waitcnt vmcnt(8)   // outstanding {t:8, t+1:8}=16 -> retires tile t
//                          //   (per-wave FIFO retire, m135)
//     s_barrier            // tile t collectively visible
//     ph1: read aT(8)+bL(4); bar; lgkm0; QD(aT,bL)  q00; bar
//     ph2: read bR(4);       bar; lgkm0; QD(aT,bR)  q01; bar
//     ph3: read aB(8);       bar; lgkm0; QD(aB,bL)  q10; bar
//     ph4:                                QD(aB,bR)  q11   (reg-only)
//
// vmcnt floor = 8 through the whole loop; single vmcnt(0) before the last
// tile only. Tile t+1's loads get the full tile-t compute (~4 phases) of
// latency cover. Each phase's ds-reads are lgkm0-drained before its MFMA;
// all reads of buf d complete by ph3's trailing barrier.
//
// LDS swizzle (BK=64 rows = 128 B = 8 chunks): stored 16B-chunk c of row r
// holds global chunk c ^ (r&7); staging pre-swizzles the GLOBAL source chunk
// ((tid&7)^((tid>>3)&7)) so the LDS destination stays linear
// (global_load_lds requirement); reads use chunk (s*4+quad) ^ (row&7).
// 2 lanes/bank worst case (free, m136).
// ---------------------------------------------------------------------------
__global__ __launch_bounds__(512, 2) void gemm_bt(const unsigned short* __restrict__ A,
                                                  const unsigned short* __restrict__ B,
                                                  float* __restrict__ C) {
    extern __shared__ unsigned short smem[];

    const int tid  = threadIdx.x;
    const int wave = tid >> 6;
    const int lane = tid & 63;

    const int n0 = blockIdx.x * 256;
    const int m0 = blockIdx.y * 256;

    // ---- staging addressing: one G::load = 64 rows x 128B = 8 KiB ----
    const int srow = tid >> 3;                               // 0..63
    const int sg8  = ((tid & 7) ^ ((tid >> 3) & 7)) * 8;     // swizzled src chunk
    const unsigned short* gA = A + (size_t)(m0 + srow) * KDIM + sg8;
    const unsigned short* gB = B + (size_t)(n0 + srow) * KDIM + sg8;
    const int woff = wave * 512;   // wave slice (1 KiB) within a G::load

    // ---- read addressing (wave (wm,wn) owns a 128x64 output block) ----
    const int wm   = wave >> 2;    // 0..1
    const int wn   = wave & 3;     // 0..3
    const int quad = lane >> 4;    // 0..3
    const int r    = lane & 15;

    // aoff[mi*2+s]: A tile row wm*128 + mi*16 + r (mi 0..7), K-slot s (0..1)
    int aoff[16], boff[8];
#pragma unroll
    for (int mi = 0; mi < 8; ++mi)
#pragma unroll
        for (int s = 0; s < 2; ++s) {
            const int row = wm * 128 + mi * 16 + r;
            aoff[mi * 2 + s] = row * 64 + (((s * 4 + quad) ^ (row & 7)) * 8);
        }
#pragma unroll
    for (int ni = 0; ni < 4; ++ni)
#pragma unroll
        for (int s = 0; s < 2; ++s) {
            const int row = wn * 64 + ni * 16 + r;
            boff[ni * 2 + s] = row * 64 + (((s * 4 + quad) ^ (row & 7)) * 8);
        }

    f32x4 acc[8][4] = {};
    bf16x8 aT[8], aB_[8], bL[4], bR[4];

#define ABUF(d) (smem + (d) * 32768)
#define BBUF(d) (smem + (d) * 32768 + 16384)
// stage half H (rows H*128..H*128+127) of A/B tile T into buf d (2 gloads)
#define SGA(d, T, H) do {                                                   \
        const unsigned short* g_ = gA + (size_t)(T) * BK + (size_t)(H) * 128 * KDIM; \
        gload_lds16(g_,                     ABUF(d) + (H) * 8192 + woff);   \
        gload_lds16(g_ + (size_t)64 * KDIM, ABUF(d) + (H) * 8192 + 4096 + woff); \
    } while (0)
#define SGB(d, T, H) do {                                                   \
        const unsigned short* g_ = gB + (size_t)(T) * BK + (size_t)(H) * 128 * KDIM; \
        gload_lds16(g_,                     BBUF(d) + (H) * 8192 + woff);   \
        gload_lds16(g_ + (size_t)64 * KDIM, BBUF(d) + (H) * 8192 + 4096 + woff); \
    } while (0)
#define STAGEFULL(d, T) do { SGA(d, T, 0); SGA(d, T, 1);                    \
                             SGB(d, T, 0); SGB(d, T, 1); } while (0)
// A-frags: half=0 -> aoff[0..7] (mi 0..3), half=1 -> aoff[8..15] (mi 4..7)
#define RDA(F, d, half) do {                                                \
        _Pragma("unroll")                                                   \
        for (int j = 0; j < 8; ++j)                                         \
            F[j] = *(const bf16x8*)(ABUF(d) + aoff[(half) * 8 + j]);        \
    } while (0)
#define RDB(F, d, nh) do {                                                  \
        _Pragma("unroll")                                                   \
        for (int j = 0; j < 4; ++j)                                         \
            F[j] = *(const bf16x8*)(BBUF(d) + boff[(nh) * 4 + j]);          \
    } while (0)
#define QD(AF, BF, MH, NH) do {                                             \
        __builtin_amdgcn_s_setprio(1);                                      \
        _Pragma("unroll")                                                   \
        for (int mi = 0; mi < 4; ++mi)                                      \
            _Pragma("unroll")                                               \
            for (int ni = 0; ni < 2; ++ni)                                  \
                _Pragma("unroll")                                           \
                for (int s = 0; s < 2; ++s)                                 \
                    acc[(MH) * 4 + mi][(NH) * 2 + ni] =                     \
                        __builtin_amdgcn_mfma_f32_16x16x32_bf16(            \
                            AF[mi * 2 + s], BF[ni * 2 + s],                 \
                            acc[(MH) * 4 + mi][(NH) * 2 + ni], 0, 0, 0);    \
        __builtin_amdgcn_s_setprio(0);                                      \
    } while (0)
#define FEN asm volatile("" ::: "memory")
#define BARX do { FEN; __builtin_amdgcn_s_barrier(); FEN; } while (0)
#define LG0  asm volatile("s_waitcnt lgkmcnt(0)" ::: "memory")
#define VMW(N) asm volatile("s_waitcnt vmcnt(" #N ")" ::: "memory")

#define TILEBODY(d) do {                                                    \
        /*ph1*/ RDA(aT, d, 0); RDB(bL, d, 0);                               \
                BARX; LG0; QD(aT, bL, 0, 0); BARX;                          \
        /*ph2*/ RDB(bR, d, 1);                                              \
                BARX; LG0; QD(aT, bR, 0, 1); BARX;                          \
        /*ph3*/ RDA(aB_, d, 1);                                             \
                BARX; LG0; QD(aB_, bL, 1, 0); BARX;                         \
        /*ph4*/ QD(aB_, bR, 1, 1);                                          \
    } while (0)

    // ---- prologue: tile 0 -> buf0 (8 loads outstanding) ----
    STAGEFULL(0, 0);

    // ---- main loop: tiles 2i (buf0) and 2i+1 (buf1), i = 0..30 ----
    for (int i = 0; i < 31; ++i) {
        STAGEFULL(1, 2 * i + 1);   // buf1's last readers: tile 2i-1, drained
        VMW(8);                     // retires tile 2i
        BARX;
        TILEBODY(0);
        STAGEFULL(0, 2 * i + 2);   // buf0's readers (tile 2i) drained at ph3
        VMW(8);                     // retires tile 2i+1
        BARX;
        TILEBODY(1);
    }
    // ---- tail: tiles 62, 63 ----
    STAGEFULL(1, 63);
    VMW(8);                         // retires tile 62
    BARX;
    TILEBODY(0);
    VMW(0);                         // retires tile 63 (only full drain)
    BARX;
    TILEBODY(1);

#undef TILEBODY
#undef VMW
#undef LG0
#undef BARX
#undef FEN
#undef QD
#undef RDB
#undef RDA
#undef STAGEFULL
#undef SGB
#undef SGA
#undef BBUF
#undef ABUF

    // C/D layout: col = lane&15, row = quad*4 + reg  [verified m89/m91]
#pragma unroll
    for (int mi = 0; mi < 8; ++mi) {
        const int row = m0 + wm * 128 + mi * 16 + quad * 4;
#pragma unroll
        for (int ni = 0; ni < 4; ++ni) {
            const int col = n0 + wn * 64 + ni * 16 + r;
            float* p = C + (size_t)row * NDIM + col;
#pragma unroll
            for (int rr = 0; rr < 4; ++rr)
                p[(size_t)rr * NDIM] = acc[mi][ni][rr];
        }
    }
}

// ---------------------------------------------------------------------------
extern "C" void kernel_launch(void* const* d_in, const int* in_sizes, int n_in,
                              void* d_out, int out_size, void* d_ws, size_t ws_size,
                              hipStream_t stream) {
    const float* A = (const float*)d_in[0];   // [8,1024,4096] == [8192,4096]
    const float* W = (const float*)d_in[1];   // [4096,4096]  (N,K)
    float* out = (float*)d_out;               // [8192,4096] fp32

    unsigned short* Abf = (unsigned short*)d_ws;                       // 64 MiB
    unsigned short* Wbf = Abf + (size_t)M_TOTAL * KDIM;                // 32 MiB

    const long nA = (long)M_TOTAL * KDIM;     // 33,554,432
    const long nW = (long)NDIM * KDIM;        // 16,777,216
    const long nTot = nA + nW;

    cvt_both<<<(int)(nTot / 8 / 256), 256, 0, stream>>>(A, Abf, nA, W, Wbf);

    // 128 KiB dynamic LDS needs the attribute raised once (host-side call,
    // graph-capture safe: not a stream op)
    static bool attr_done = false;
    if (!attr_done) {
        hipFuncSetAttribute((const void*)gemm_bt,
                            hipFuncAttributeMaxDynamicSharedMemorySize, 128 * 1024);
        attr_done = true;
    }

    dim3 grid(NDIM / 256, M_TOTAL / 256);     // (16, 32) = 512 blocks
    gemm_bt<<<grid, 512, 128 * 1024, stream>>>(Abf, Wbf, out);
}